// Round 2
// baseline (6150.322 us; speedup 1.0000x reference)
//
#include <hip/hip_runtime.h>
#include <math.h>

typedef float f32x4 __attribute__((ext_vector_type(4)));
typedef __bf16 bf16x8 __attribute__((ext_vector_type(8)));
typedef unsigned short u16x8 __attribute__((ext_vector_type(8)));

static constexpr int Dm  = 2048;
static constexpr int Tm  = 2048;
static constexpr int Hm  = 16;
static constexpr int KVm = 8;
static constexpr int HDm = 128;
static constexpr int FFm = 6144;
static constexpr int Vm  = 32000;

__device__ __forceinline__ float b2f(unsigned short u) {
  unsigned int x = ((unsigned int)u) << 16;
  return __builtin_bit_cast(float, x);
}
__device__ __forceinline__ unsigned short f2b(float f) {
  unsigned int x = __builtin_bit_cast(unsigned int, f);
  x += 0x7fffu + ((x >> 16) & 1u);   // RTNE
  return (unsigned short)(x >> 16);
}

__device__ __forceinline__ f32x4 mfma16x16x32(bf16x8 a, bf16x8 b, f32x4 c) {
  return __builtin_amdgcn_mfma_f32_16x16x32_bf16(a, b, c, 0, 0, 0);
}

// Generic external-tensor loads: F32 ? fp32 : bf16
template <bool F32>
__device__ __forceinline__ float ldx(const void* p, size_t i) {
  if (F32) return ((const float*)p)[i];
  return b2f(((const unsigned short*)p)[i]);
}
template <bool F32>
__device__ __forceinline__ void ld8(const void* p, size_t i, float* o) {
  if (F32) {
    const float* q = (const float*)p + i;
    f32x4 a = *(const f32x4*)q;
    f32x4 b = *(const f32x4*)(q + 4);
    o[0] = a.x; o[1] = a.y; o[2] = a.z; o[3] = a.w;
    o[4] = b.x; o[5] = b.y; o[6] = b.z; o[7] = b.w;
  } else {
    u16x8 v = *(const u16x8*)((const unsigned short*)p + i);
#pragma unroll
    for (int j = 0; j < 8; ++j) o[j] = b2f(v[j]);
  }
}

// ---------------------------------------------------------------------------
// Dtype probe: even u16 words of fp32 data have uniform-random exponent fields;
// bf16 data (normal*0.02) has exponents ~[110,125]. flag=1 -> fp32.
__global__ void detect_k(const unsigned short* __restrict__ emb, int* __restrict__ flag) {
  if (threadIdx.x == 0 && blockIdx.x == 0) {
    int wild = 0;
    for (int i = 0; i < 256; ++i) {
      unsigned short u = emb[2 * i];
      int ex = (u >> 7) & 0xFF;
      if (ex > 170 || ex < 80) ++wild;
    }
    *flag = (wild >= 64) ? 1 : 0;
  }
}

// RoPE tables: cos/sin[t][i], i<64 (the two HD/2 halves are identical)
__global__ void rope_tables_k(float* __restrict__ cosT, float* __restrict__ sinT) {
  int t = blockIdx.x;
  int i = threadIdx.x;      // 0..63
  double inv = pow(1000000.0, -(double)i / 64.0);
  double ang = (double)t * inv;
  cosT[t * 64 + i] = (float)cos(ang);
  sinT[t * 64 + i] = (float)sin(ang);
}

// Embedding gather: x_f32[t][d] = emb[ids[t]][d]
template <bool F32>
__global__ __launch_bounds__(256) void embed_k(const int* __restrict__ ids,
                                               const void* __restrict__ emb,
                                               float* __restrict__ x,
                                               const int* __restrict__ flag) {
  if (*flag != (F32 ? 1 : 0)) return;
  int t = blockIdx.x;
  int d0 = threadIdx.x * 8;
  int id = ids[t];
  float o[8];
  ld8<F32>(emb, (size_t)id * Dm + d0, o);
  float* xr = x + (size_t)t * Dm + d0;
#pragma unroll
  for (int j = 0; j < 8; ++j) xr[j] = o[j];
}

// Row RMSNorm over D=2048: y_bf16 = x_f32 * rsqrt(mean(x^2)+eps) * g
template <bool F32>
__global__ __launch_bounds__(256) void rmsnorm_k(const float* __restrict__ x,
                                                 const void* __restrict__ g,
                                                 unsigned short* __restrict__ y,
                                                 const int* __restrict__ flag) {
  if (*flag != (F32 ? 1 : 0)) return;
  int t = blockIdx.x;
  const float* xr = x + (size_t)t * Dm;
  float vals[8];
  float s = 0.f;
#pragma unroll
  for (int i = 0; i < 8; ++i) {
    float vv = xr[threadIdx.x + i * 256];
    vals[i] = vv;
    s += vv * vv;
  }
#pragma unroll
  for (int off = 32; off; off >>= 1) s += __shfl_xor(s, off);
  __shared__ float red[4];
  if ((threadIdx.x & 63) == 0) red[threadIdx.x >> 6] = s;
  __syncthreads();
  s = (red[0] + red[1]) + (red[2] + red[3]);
  float r = rsqrtf(s * (1.f / Dm) + 1e-6f);
  unsigned short* yr = y + (size_t)t * Dm;
#pragma unroll
  for (int i = 0; i < 8; ++i) {
    int d = threadIdx.x + i * 256;
    yr[d] = f2b(vals[i] * r * ldx<F32>(g, d));
  }
}

// Per-(t,head) RMSNorm over HD=128 (scale nrm) then RoPE. One wave per row.
template <bool F32>
__global__ __launch_bounds__(256) void qknorm_rope_k(unsigned short* __restrict__ q,
                                                     const void* __restrict__ nrm,
                                                     const float* __restrict__ cosT,
                                                     const float* __restrict__ sinT,
                                                     int nheads,
                                                     const int* __restrict__ flag) {
  if (*flag != (F32 ? 1 : 0)) return;
  int gw = (int)((blockIdx.x * blockDim.x + threadIdx.x) >> 6);
  int lane = threadIdx.x & 63;
  int t = gw / nheads, h = gw % nheads;
  unsigned short* row = q + ((size_t)t * nheads + h) * HDm;
  float x1 = b2f(row[lane]);
  float x2 = b2f(row[lane + 64]);
  float s = x1 * x1 + x2 * x2;
#pragma unroll
  for (int off = 32; off; off >>= 1) s += __shfl_xor(s, off);
  float r = rsqrtf(s * (1.f / HDm) + 1e-6f);
  float y1 = x1 * r * ldx<F32>(nrm, lane);
  float y2 = x2 * r * ldx<F32>(nrm, lane + 64);
  float c = cosT[t * 64 + lane];
  float sn = sinT[t * 64 + lane];
  row[lane]      = f2b(y1 * c - y2 * sn);
  row[lane + 64] = f2b(y2 * c + y1 * sn);
}

// ---------------------------------------------------------------------------
// GEMM: C[M,N] = A[M,K] @ B.  A bf16 row-major (lda=K), internal.
// B external (dtype per F32B). BT=false: B is [K,N]. BT=true: B is [N,K].
// EPI=0: C store (bf16 unless OUTF32). EPI=1: C f32 +=. EPI=2: C bf16 silu-mult.
template <int EPI, bool BT, bool F32B, bool OUTF32>
__global__ __launch_bounds__(256) void gemm_k(const unsigned short* __restrict__ A,
                                              const void* __restrict__ B,
                                              void* __restrict__ C,
                                              int M, int N, int K,
                                              const int* __restrict__ flag) {
  if (*flag != (F32B ? 1 : 0)) return;
  (void)M;
  __shared__ unsigned short As[128][40];  // [m][k] pad 40
  __shared__ unsigned short Bs[128][40];  // [n][k] pad 40
  const int tid = threadIdx.x;
  const int bm = blockIdx.y, bn = blockIdx.x;
  const int w = tid >> 6, lane = tid & 63;
  const int wm = (w >> 1) * 64, wn = (w & 1) * 64;
  const int lr = lane & 15, kq = (lane >> 4) * 8;
  const int rowA0 = bm * 128, colB0 = bn * 128;

  f32x4 acc[4][4] = {};

  for (int k0 = 0; k0 < K; k0 += 32) {
    __syncthreads();
    // stage A: 128x32 (always bf16)
#pragma unroll
    for (int i = 0; i < 2; ++i) {
      int e = tid + i * 256;
      int r = e >> 2, c = (e & 3) * 8;
      u16x8 val = *(const u16x8*)(A + (size_t)(rowA0 + r) * K + k0 + c);
      *(u16x8*)&As[r][c] = val;
    }
    if (BT) {
#pragma unroll
      for (int i = 0; i < 2; ++i) {
        int e = tid + i * 256;
        int r = e >> 2, c = (e & 3) * 8;
        if (!F32B) {
          u16x8 val = *(const u16x8*)((const unsigned short*)B +
                                      (size_t)(colB0 + r) * K + k0 + c);
          *(u16x8*)&Bs[r][c] = val;
        } else {
          float o[8];
          ld8<true>(B, (size_t)(colB0 + r) * K + k0 + c, o);
#pragma unroll
          for (int j = 0; j < 8; ++j) Bs[r][c + j] = f2b(o[j]);
        }
      }
    } else {
#pragma unroll
      for (int i = 0; i < 2; ++i) {
        int e = tid + i * 256;
        int kr = e >> 4, nc = (e & 15) * 8;
        float o[8];
        ld8<F32B>(B, (size_t)(k0 + kr) * N + colB0 + nc, o);
#pragma unroll
        for (int j = 0; j < 8; ++j) Bs[nc + j][kr] = f2b(o[j]);
      }
    }
    __syncthreads();

    bf16x8 av[4], bv[4];
#pragma unroll
    for (int m = 0; m < 4; ++m)
      av[m] = __builtin_bit_cast(bf16x8, *(const u16x8*)&As[wm + m * 16 + lr][kq]);
#pragma unroll
    for (int n = 0; n < 4; ++n)
      bv[n] = __builtin_bit_cast(bf16x8, *(const u16x8*)&Bs[wn + n * 16 + lr][kq]);
#pragma unroll
    for (int m = 0; m < 4; ++m)
#pragma unroll
      for (int n = 0; n < 4; ++n)
        acc[m][n] = mfma16x16x32(av[m], bv[n], acc[m][n]);
  }

  // epilogue: C/D layout col=lane&15, row=(lane>>4)*4+reg  [verified m89/m91]
  const int r0 = bm * 128 + wm + (lane >> 4) * 4;
  const int c0 = bn * 128 + wn + lr;
#pragma unroll
  for (int m = 0; m < 4; ++m)
#pragma unroll
    for (int n = 0; n < 4; ++n)
#pragma unroll
      for (int j = 0; j < 4; ++j) {
        int r = r0 + m * 16 + j;
        int c = c0 + n * 16;
        size_t idx = (size_t)r * N + c;
        if (EPI == 0) {
          if (OUTF32) ((float*)C)[idx] = acc[m][n][j];
          else        ((unsigned short*)C)[idx] = f2b(acc[m][n][j]);
        } else if (EPI == 1) {
          ((float*)C)[idx] += acc[m][n][j];
        } else {
          unsigned short* Cb = (unsigned short*)C;
          float gg = b2f(Cb[idx]);
          gg = gg / (1.f + expf(-gg));   // silu of previously-stored h@W1
          Cb[idx] = f2b(gg * acc[m][n][j]);
        }
      }
}

// ---------------------------------------------------------------------------
// Flash attention, GQA G=2. One wave per q-row, 4 rows/block, k/v tiles 64x128.
// All operands internal bf16 — no dtype variants needed.
__global__ __launch_bounds__(256) void attn_k(const unsigned short* __restrict__ q,
                                              const unsigned short* __restrict__ k,
                                              const unsigned short* __restrict__ v,
                                              unsigned short* __restrict__ o) {
  __shared__ float kf[64][132];
  __shared__ float vf[64][132];
  __shared__ float qf[4][132];
  const int h = blockIdx.y;
  const int t0 = blockIdx.x * 4;
  const int w = threadIdx.x >> 6, lane = threadIdx.x & 63;
  const int t = t0 + w;
  const int kv = h >> 1;

  {  // stage this wave's q row (already normed+roped)
    const unsigned short* qr = q + ((size_t)t * Hm + h) * HDm;
    qf[w][lane * 2]     = b2f(qr[lane * 2]);
    qf[w][lane * 2 + 1] = b2f(qr[lane * 2 + 1]);
  }

  float m = -3.0e38f, l = 0.f, o1 = 0.f, o2 = 0.f;
  const int ntiles = (t0 + 3) / 64 + 1;

  for (int tile = 0; tile < ntiles; ++tile) {
    const int s0 = tile * 64;
    __syncthreads();
#pragma unroll
    for (int i = 0; i < 4; ++i) {
      int e = threadIdx.x + i * 256;        // 1024 vec8 slots
      int r = e >> 4, c = (e & 15) * 8;
      size_t base = ((size_t)(s0 + r) * KVm + kv) * HDm + c;
      u16x8 k8 = *(const u16x8*)(k + base);
      u16x8 v8 = *(const u16x8*)(v + base);
#pragma unroll
      for (int j = 0; j < 8; ++j) {
        kf[r][c + j] = b2f(k8[j]);
        vf[r][c + j] = b2f(v8[j]);
      }
    }
    __syncthreads();

    if (s0 <= t) {
      float sc = 0.f;
#pragma unroll
      for (int d = 0; d < 128; d += 4) {
        f32x4 kk = *(const f32x4*)&kf[lane][d];
        f32x4 qq = *(const f32x4*)&qf[w][d];
        sc += kk.x * qq.x + kk.y * qq.y + kk.z * qq.z + kk.w * qq.w;
      }
      sc *= 0.08838834764831845f;  // 1/sqrt(128)
      const bool valid = (s0 + lane) <= t;
      float scm = valid ? sc : -3.0e38f;
#pragma unroll
      for (int off = 32; off; off >>= 1) scm = fmaxf(scm, __shfl_xor(scm, off));
      const float mnew = fmaxf(m, scm);
      const float alpha = expf(m - mnew);
      float pp = valid ? expf(sc - mnew) : 0.f;
      float psum = pp;
#pragma unroll
      for (int off = 32; off; off >>= 1) psum += __shfl_xor(psum, off);
      l = l * alpha + psum;
      m = mnew;
      o1 *= alpha;
      o2 *= alpha;
#pragma unroll 8
      for (int s2 = 0; s2 < 64; ++s2) {
        float ps = __shfl(pp, s2);
        o1 += ps * vf[s2][lane];
        o2 += ps * vf[s2][lane + 64];
      }
    }
  }

  const float inv = 1.f / l;
  unsigned short* orow = o + ((size_t)t * Hm + h) * HDm;
  orow[lane]      = f2b(o1 * inv);
  orow[lane + 64] = f2b(o2 * inv);
}

// ---------------------------------------------------------------------------
extern "C" void kernel_launch(void* const* d_in, const int* in_sizes, int n_in,
                              void* d_out, int out_size, void* d_ws, size_t ws_size,
                              hipStream_t stream) {
  (void)in_sizes; (void)n_in; (void)out_size; (void)ws_size;
  const int* ids  = (const int*)d_in[0];
  const void* emb = d_in[1];
  const void* Wq  = d_in[2];
  const void* Wk  = d_in[3];
  const void* Wv  = d_in[4];
  const void* Wo  = d_in[5];
  const void* qn  = d_in[6];
  const void* kn  = d_in[7];
  const void* W1  = d_in[8];
  const void* W2  = d_in[9];
  const void* W3  = d_in[10];
  const void* ln1 = d_in[11];
  const void* ln2 = d_in[12];
  const void* lnf = d_in[13];

  char* p = (char*)d_ws;
  int* flag          = (int*)p;            p += 256;
  float* xf          = (float*)p;          p += (size_t)Tm * Dm * 4;
  unsigned short* hb = (unsigned short*)p; p += (size_t)Tm * Dm * 2;
  unsigned short* qb = (unsigned short*)p; p += (size_t)Tm * Hm * HDm * 2;
  unsigned short* kb = (unsigned short*)p; p += (size_t)Tm * KVm * HDm * 2;
  unsigned short* vb = (unsigned short*)p; p += (size_t)Tm * KVm * HDm * 2;
  unsigned short* ob = (unsigned short*)p; p += (size_t)Tm * Hm * HDm * 2;
  float* cosT        = (float*)p;          p += (size_t)Tm * 64 * 4;
  float* sinT        = (float*)p;          p += (size_t)Tm * 64 * 4;
  unsigned short* g1 = qb;  // FFN phase reuses attn buffers (same 25.2MB span)

  // per-element external strides (fp32 vs bf16 both supported via templates)
  detect_k<<<1, 64, 0, stream>>>((const unsigned short*)emb, flag);
  rope_tables_k<<<Tm, 64, 0, stream>>>(cosT, sinT);
  embed_k<false><<<Tm, 256, 0, stream>>>(ids, emb, xf, flag);
  embed_k<true ><<<Tm, 256, 0, stream>>>(ids, emb, xf, flag);

#define BOTH(call_f, call_t) do { call_f; call_t; } while (0)

  for (int l = 0; l < 2; ++l) {
    const size_t offQ = (size_t)l * Dm * (Hm * HDm);
    const size_t offK = (size_t)l * Dm * (KVm * HDm);
    const size_t offO = (size_t)l * (Hm * HDm) * Dm;
    const size_t offF = (size_t)l * Dm * FFm;
    auto eo = [](const void* b, size_t elems, bool f32_unused) { (void)f32_unused; return b; };
    (void)eo;
    const unsigned short* Wq_b = (const unsigned short*)Wq + offQ;
    const float*          Wq_f = (const float*)Wq + offQ;
    const unsigned short* Wk_b = (const unsigned short*)Wk + offK;
    const float*          Wk_f = (const float*)Wk + offK;
    const unsigned short* Wv_b = (const unsigned short*)Wv + offK;
    const float*          Wv_f = (const float*)Wv + offK;
    const unsigned short* Wo_b = (const unsigned short*)Wo + offO;
    const float*          Wo_f = (const float*)Wo + offO;
    const unsigned short* W1_b = (const unsigned short*)W1 + offF;
    const float*          W1_f = (const float*)W1 + offF;
    const unsigned short* W2_b = (const unsigned short*)W2 + offF;
    const float*          W2_f = (const float*)W2 + offF;
    const unsigned short* W3_b = (const unsigned short*)W3 + offF;
    const float*          W3_f = (const float*)W3 + offF;
    const unsigned short* ln1_b = (const unsigned short*)ln1 + (size_t)l * Dm;
    const float*          ln1_f = (const float*)ln1 + (size_t)l * Dm;
    const unsigned short* ln2_b = (const unsigned short*)ln2 + (size_t)l * Dm;
    const float*          ln2_f = (const float*)ln2 + (size_t)l * Dm;
    const unsigned short* qn_b = (const unsigned short*)qn + (size_t)l * HDm;
    const float*          qn_f = (const float*)qn + (size_t)l * HDm;
    const unsigned short* kn_b = (const unsigned short*)kn + (size_t)l * HDm;
    const float*          kn_f = (const float*)kn + (size_t)l * HDm;

    rmsnorm_k<false><<<Tm, 256, 0, stream>>>(xf, ln1_b, hb, flag);
    rmsnorm_k<true ><<<Tm, 256, 0, stream>>>(xf, ln1_f, hb, flag);

    dim3 gq((Hm * HDm) / 128, Tm / 128), gkv((KVm * HDm) / 128, Tm / 128);
    gemm_k<0, false, false, false><<<gq, 256, 0, stream>>>(hb, Wq_b, qb, Tm, Hm * HDm, Dm, flag);
    gemm_k<0, false, true , false><<<gq, 256, 0, stream>>>(hb, Wq_f, qb, Tm, Hm * HDm, Dm, flag);
    gemm_k<0, false, false, false><<<gkv, 256, 0, stream>>>(hb, Wk_b, kb, Tm, KVm * HDm, Dm, flag);
    gemm_k<0, false, true , false><<<gkv, 256, 0, stream>>>(hb, Wk_f, kb, Tm, KVm * HDm, Dm, flag);
    gemm_k<0, false, false, false><<<gkv, 256, 0, stream>>>(hb, Wv_b, vb, Tm, KVm * HDm, Dm, flag);
    gemm_k<0, false, true , false><<<gkv, 256, 0, stream>>>(hb, Wv_f, vb, Tm, KVm * HDm, Dm, flag);

    qknorm_rope_k<false><<<(Tm * Hm) / 4, 256, 0, stream>>>(qb, qn_b, cosT, sinT, Hm, flag);
    qknorm_rope_k<true ><<<(Tm * Hm) / 4, 256, 0, stream>>>(qb, qn_f, cosT, sinT, Hm, flag);
    qknorm_rope_k<false><<<(Tm * KVm) / 4, 256, 0, stream>>>(kb, kn_b, cosT, sinT, KVm, flag);
    qknorm_rope_k<true ><<<(Tm * KVm) / 4, 256, 0, stream>>>(kb, kn_f, cosT, sinT, KVm, flag);

    attn_k<<<dim3(Tm / 4, Hm), 256, 0, stream>>>(qb, kb, vb, ob);

    dim3 gwo(Dm / 128, Tm / 128);
    gemm_k<1, false, false, false><<<gwo, 256, 0, stream>>>(ob, Wo_b, xf, Tm, Dm, Hm * HDm, flag);
    gemm_k<1, false, true , false><<<gwo, 256, 0, stream>>>(ob, Wo_f, xf, Tm, Dm, Hm * HDm, flag);

    rmsnorm_k<false><<<Tm, 256, 0, stream>>>(xf, ln2_b, hb, flag);
    rmsnorm_k<true ><<<Tm, 256, 0, stream>>>(xf, ln2_f, hb, flag);

    dim3 gff(FFm / 128, Tm / 128);
    gemm_k<0, false, false, false><<<gff, 256, 0, stream>>>(hb, W1_b, g1, Tm, FFm, Dm, flag);
    gemm_k<0, false, true , false><<<gff, 256, 0, stream>>>(hb, W1_f, g1, Tm, FFm, Dm, flag);
    gemm_k<2, false, false, false><<<gff, 256, 0, stream>>>(hb, W2_b, g1, Tm, FFm, Dm, flag);
    gemm_k<2, false, true , false><<<gff, 256, 0, stream>>>(hb, W2_f, g1, Tm, FFm, Dm, flag);
    dim3 gw3(Dm / 128, Tm / 128);
    gemm_k<1, false, false, false><<<gw3, 256, 0, stream>>>(g1, W3_b, xf, Tm, Dm, FFm, flag);
    gemm_k<1, false, true , false><<<gw3, 256, 0, stream>>>(g1, W3_f, xf, Tm, Dm, FFm, flag);
  }

  rmsnorm_k<false><<<Tm, 256, 0, stream>>>(xf, lnf, hb, flag);
  rmsnorm_k<true ><<<Tm, 256, 0, stream>>>(xf, lnf, hb, flag);

  dim3 glo(Vm / 128, Tm / 128);
  gemm_k<0, true, false, false><<<glo, 256, 0, stream>>>(hb, emb, d_out, Tm, Vm, Dm, flag);
  gemm_k<0, true, true , true ><<<glo, 256, 0, stream>>>(hb, emb, d_out, Tm, Vm, Dm, flag);
}

// Round 3
// 1929.330 us; speedup vs baseline: 3.1878x; 3.1878x over previous
//
#include <hip/hip_runtime.h>
#include <math.h>

typedef float f32x4 __attribute__((ext_vector_type(4)));
typedef __bf16 bf16x8 __attribute__((ext_vector_type(8)));
typedef unsigned short u16x8 __attribute__((ext_vector_type(8)));

static constexpr int Dm  = 2048;
static constexpr int Tm  = 2048;
static constexpr int Hm  = 16;
static constexpr int KVm = 8;
static constexpr int HDm = 128;
static constexpr int FFm = 6144;
static constexpr int Vm  = 32000;

__device__ __forceinline__ float b2f(unsigned short u) {
  unsigned int x = ((unsigned int)u) << 16;
  return __builtin_bit_cast(float, x);
}
__device__ __forceinline__ unsigned short f2b(float f) {
  unsigned int x = __builtin_bit_cast(unsigned int, f);
  x += 0x7fffu + ((x >> 16) & 1u);   // RTNE
  return (unsigned short)(x >> 16);
}
__device__ __forceinline__ f32x4 mfma16x16x32(bf16x8 a, bf16x8 b, f32x4 c) {
  return __builtin_amdgcn_mfma_f32_16x16x32_bf16(a, b, c, 0, 0, 0);
}

// ---------------------------------------------------------------------------
// RoPE tables: cos/sin[t][i], i<64 (the two HD/2 halves are identical)
__global__ void rope_tables_k(float* __restrict__ cosT, float* __restrict__ sinT) {
  int t = blockIdx.x;
  int i = threadIdx.x;      // 0..63
  double inv = pow(1000000.0, -(double)i / 64.0);
  double ang = (double)t * inv;
  cosT[t * 64 + i] = (float)cos(ang);
  sinT[t * 64 + i] = (float)sin(ang);
}

// Embedding gather: x_f32[t][d] = emb[ids[t]][d]  (emb fp32)
__global__ __launch_bounds__(256) void embed_k(const int* __restrict__ ids,
                                               const float* __restrict__ emb,
                                               float* __restrict__ x) {
  int t = blockIdx.x;
  int d0 = threadIdx.x * 8;
  int id = ids[t];
  const float* src = emb + (size_t)id * Dm + d0;
  float* dst = x + (size_t)t * Dm + d0;
  *(f32x4*)dst       = *(const f32x4*)src;
  *(f32x4*)(dst + 4) = *(const f32x4*)(src + 4);
}

// Row RMSNorm over D=2048: y_bf16 = x_f32 * rsqrt(mean(x^2)+eps) * g_f32
__global__ __launch_bounds__(256) void rmsnorm_k(const float* __restrict__ x,
                                                 const float* __restrict__ g,
                                                 unsigned short* __restrict__ y) {
  int t = blockIdx.x;
  const float* xr = x + (size_t)t * Dm;
  float vals[8];
  float s = 0.f;
#pragma unroll
  for (int i = 0; i < 8; ++i) {
    float vv = xr[threadIdx.x + i * 256];
    vals[i] = vv;
    s += vv * vv;
  }
#pragma unroll
  for (int off = 32; off; off >>= 1) s += __shfl_xor(s, off);
  __shared__ float red[4];
  if ((threadIdx.x & 63) == 0) red[threadIdx.x >> 6] = s;
  __syncthreads();
  s = (red[0] + red[1]) + (red[2] + red[3]);
  float r = rsqrtf(s * (1.f / Dm) + 1e-6f);
  unsigned short* yr = y + (size_t)t * Dm;
#pragma unroll
  for (int i = 0; i < 8; ++i) {
    int d = threadIdx.x + i * 256;
    yr[d] = f2b(vals[i] * r * g[d]);
  }
}

// Per-(t,head) RMSNorm over HD=128 (fp32 scale) then RoPE. One wave per row.
__global__ __launch_bounds__(256) void qknorm_rope_k(unsigned short* __restrict__ q,
                                                     const float* __restrict__ nrm,
                                                     const float* __restrict__ cosT,
                                                     const float* __restrict__ sinT,
                                                     int nheads) {
  int gw = (int)((blockIdx.x * blockDim.x + threadIdx.x) >> 6);
  int lane = threadIdx.x & 63;
  int t = gw / nheads, h = gw % nheads;
  unsigned short* row = q + ((size_t)t * nheads + h) * HDm;
  float x1 = b2f(row[lane]);
  float x2 = b2f(row[lane + 64]);
  float s = x1 * x1 + x2 * x2;
#pragma unroll
  for (int off = 32; off; off >>= 1) s += __shfl_xor(s, off);
  float r = rsqrtf(s * (1.f / HDm) + 1e-6f);
  float y1 = x1 * r * nrm[lane];
  float y2 = x2 * r * nrm[lane + 64];
  float c = cosT[t * 64 + lane];
  float sn = sinT[t * 64 + lane];
  row[lane]      = f2b(y1 * c - y2 * sn);
  row[lane + 64] = f2b(y2 * c + y1 * sn);
}

// ---------------------------------------------------------------------------
// Weight convert+transpose: W fp32 [K][N] -> Wt bf16 [N][K]
__global__ __launch_bounds__(256) void cvtT_k(const float* __restrict__ W,
                                              unsigned short* __restrict__ Wt,
                                              int K, int N) {
  __shared__ __align__(16) unsigned short tile[64][68];
  const int n0 = blockIdx.x * 64, k0 = blockIdx.y * 64;
  const int tid = threadIdx.x;
#pragma unroll
  for (int i = 0; i < 4; ++i) {
    int e = tid + i * 256;
    int r = e >> 4, c4 = (e & 15) * 4;
    f32x4 v = *(const f32x4*)(W + (size_t)(k0 + r) * N + n0 + c4);
    tile[r][c4 + 0] = f2b(v.x);
    tile[r][c4 + 1] = f2b(v.y);
    tile[r][c4 + 2] = f2b(v.z);
    tile[r][c4 + 3] = f2b(v.w);
  }
  __syncthreads();
#pragma unroll
  for (int i = 0; i < 2; ++i) {
    int e = tid + i * 256;
    int rr = e >> 3, cc = (e & 7) * 8;
    u16x8 o;
#pragma unroll
    for (int j = 0; j < 8; ++j) o[j] = tile[cc + j][rr];
    *(u16x8*)(Wt + (size_t)(n0 + rr) * K + k0 + cc) = o;
  }
}

// ---------------------------------------------------------------------------
// GEMM: C[M,N] = A[M,K] @ B^T, A bf16 row-major [M][K], B row-major [N][K].
// BF32: B is fp32 (logits/emb). else bf16 (pre-transposed weights).
// EPI=0: store (bf16, or fp32 if OUTF32). EPI=1: C f32 +=. EPI=2: bf16 silu-mult.
// grid: (M/128, N/128) — bm on x so consecutive blocks share the B panel in L2.
template <int EPI, bool BF32, bool OUTF32>
__global__ __launch_bounds__(256) void gemm_k(const unsigned short* __restrict__ A,
                                              const void* __restrict__ B,
                                              void* __restrict__ C,
                                              int N, int K) {
  __shared__ __align__(16) unsigned short As[128][40];
  __shared__ __align__(16) unsigned short Bs[128][40];
  const int tid = threadIdx.x;
  const int bm = blockIdx.x, bn = blockIdx.y;
  const int w = tid >> 6, lane = tid & 63;
  const int wm = (w >> 1) * 64, wn = (w & 1) * 64;
  const int lr = lane & 15, kq = (lane >> 4) * 8;
  const int rowA0 = bm * 128, colB0 = bn * 128;

  f32x4 acc[4][4] = {};

  for (int k0 = 0; k0 < K; k0 += 32) {
    __syncthreads();
#pragma unroll
    for (int i = 0; i < 2; ++i) {
      int e = tid + i * 256;
      int r = e >> 2, c = (e & 3) * 8;
      *(u16x8*)&As[r][c] = *(const u16x8*)(A + (size_t)(rowA0 + r) * K + k0 + c);
      if (!BF32) {
        *(u16x8*)&Bs[r][c] = *(const u16x8*)((const unsigned short*)B +
                                             (size_t)(colB0 + r) * K + k0 + c);
      } else {
        const float* bp = (const float*)B + (size_t)(colB0 + r) * K + k0 + c;
        f32x4 v0 = *(const f32x4*)bp;
        f32x4 v1 = *(const f32x4*)(bp + 4);
        Bs[r][c + 0] = f2b(v0.x); Bs[r][c + 1] = f2b(v0.y);
        Bs[r][c + 2] = f2b(v0.z); Bs[r][c + 3] = f2b(v0.w);
        Bs[r][c + 4] = f2b(v1.x); Bs[r][c + 5] = f2b(v1.y);
        Bs[r][c + 6] = f2b(v1.z); Bs[r][c + 7] = f2b(v1.w);
      }
    }
    __syncthreads();

    bf16x8 av[4], bv[4];
#pragma unroll
    for (int m = 0; m < 4; ++m)
      av[m] = __builtin_bit_cast(bf16x8, *(const u16x8*)&As[wm + m * 16 + lr][kq]);
#pragma unroll
    for (int n = 0; n < 4; ++n)
      bv[n] = __builtin_bit_cast(bf16x8, *(const u16x8*)&Bs[wn + n * 16 + lr][kq]);
#pragma unroll
    for (int m = 0; m < 4; ++m)
#pragma unroll
      for (int n = 0; n < 4; ++n)
        acc[m][n] = mfma16x16x32(av[m], bv[n], acc[m][n]);
  }

  // C/D layout: col=lane&15, row=(lane>>4)*4+reg  [verified]
  const int r0 = rowA0 + wm + (lane >> 4) * 4;
  const int c0 = colB0 + wn + lr;
#pragma unroll
  for (int m = 0; m < 4; ++m)
#pragma unroll
    for (int n = 0; n < 4; ++n)
#pragma unroll
      for (int j = 0; j < 4; ++j) {
        int r = r0 + m * 16 + j;
        int c = c0 + n * 16;
        size_t idx = (size_t)r * N + c;
        if (EPI == 0) {
          if (OUTF32) ((float*)C)[idx] = acc[m][n][j];
          else        ((unsigned short*)C)[idx] = f2b(acc[m][n][j]);
        } else if (EPI == 1) {
          ((float*)C)[idx] += acc[m][n][j];
        } else {
          unsigned short* Cb = (unsigned short*)C;
          float gg = b2f(Cb[idx]);
          gg = gg / (1.f + __expf(-gg));   // silu of previously-stored h@W1
          Cb[idx] = f2b(gg * acc[m][n][j]);
        }
      }
}

// ---------------------------------------------------------------------------
// MFMA flash attention, GQA G=2. Block: 4 waves, 64 q-rows, head h.
// KV tiles of 64. Q in registers; K LDS XOR-swizzled; V LDS transposed+swizzled.
__global__ __launch_bounds__(256) void attn_k(const unsigned short* __restrict__ qg,
                                              const unsigned short* __restrict__ kg,
                                              const unsigned short* __restrict__ vg,
                                              unsigned short* __restrict__ og) {
  __shared__ __align__(16) unsigned short Ks[64 * 128];   // swizzled rows of K
  __shared__ __align__(16) unsigned short Vt[128 * 72];   // Vt[d][kv^swz]
  __shared__ __align__(16) unsigned short Pl[4 * 16 * 72];// per-wave P rows
  const int h = blockIdx.y, bx = blockIdx.x, t0 = bx * 64;
  const int w = threadIdx.x >> 6, lane = threadIdx.x & 63;
  const int lr = lane & 15, hi = lane >> 4;   // hi 0..3
  const int kvh = h >> 1;

  // Q fragments: A row = lr -> q row t0+w*16+lr; k-quad = hi*8 within 32-chunk
  bf16x8 qa[4];
  {
    const unsigned short* qrow = qg + ((size_t)(t0 + w * 16 + lr) * Hm + h) * HDm;
#pragma unroll
    for (int ks = 0; ks < 4; ++ks)
      qa[ks] = __builtin_bit_cast(bf16x8, *(const u16x8*)(qrow + ks * 32 + hi * 8));
  }

  f32x4 oa[8] = {};                     // O[qrow][d], 8 d-tiles of 16
  float mj[4], lj[4];
#pragma unroll
  for (int j = 0; j < 4; ++j) { mj[j] = -3.0e38f; lj[j] = 0.f; }

  const int ntiles = bx + 1;
  for (int tile = 0; tile < ntiles; ++tile) {
    const int s0 = tile * 64;
    __syncthreads();
    // stage K (vector, swizzled) and V^T (scalar, d-keyed swizzle)
#pragma unroll
    for (int i = 0; i < 4; ++i) {
      int e = threadIdx.x + i * 256;
      int r = e >> 4, c = (e & 15) * 8;
      size_t base = ((size_t)(s0 + r) * KVm + kvh) * HDm + c;
      u16x8 kk = *(const u16x8*)(kg + base);
      int kbyte = (r * 256 + c * 2) ^ ((r & 7) << 4);
      *(u16x8*)((char*)Ks + kbyte) = kk;
      u16x8 vv = *(const u16x8*)(vg + base);
#pragma unroll
      for (int j = 0; j < 8; ++j) {
        int d = c + j;
        Vt[d * 72 + (r ^ (((d >> 3) & 7) << 3))] = vv[j];
      }
    }
    __syncthreads();

    // S = Q @ K^T  (4 kv-subtiles of 16)
    f32x4 s[4] = {};
#pragma unroll
    for (int ks = 0; ks < 4; ++ks)
#pragma unroll
      for (int nt = 0; nt < 4; ++nt) {
        int krow = nt * 16 + lr;
        int kbyte = (krow * 256 + (ks * 32 + hi * 8) * 2) ^ ((krow & 7) << 4);
        bf16x8 kf = __builtin_bit_cast(bf16x8, *(const u16x8*)((char*)Ks + kbyte));
        s[nt] = mfma16x16x32(qa[ks], kf, s[nt]);
      }

    // scale + causal mask (only the diagonal tile needs masking)
    float p[4][4];
    const bool maskt = (tile == ntiles - 1);
#pragma unroll
    for (int nt = 0; nt < 4; ++nt)
#pragma unroll
      for (int j = 0; j < 4; ++j) {
        float val = s[nt][j] * 0.08838834764831845f;
        if (maskt && (s0 + nt * 16 + lr) > (t0 + w * 16 + hi * 4 + j)) val = -1e30f;
        p[nt][j] = val;
      }

    // online softmax per q-row (4 rows/lane), reduce over 16-lane lr group
#pragma unroll
    for (int j = 0; j < 4; ++j) {
      float mx = fmaxf(fmaxf(p[0][j], p[1][j]), fmaxf(p[2][j], p[3][j]));
#pragma unroll
      for (int msk = 1; msk < 16; msk <<= 1) mx = fmaxf(mx, __shfl_xor(mx, msk));
      float mnew = fmaxf(mj[j], mx);
      float alpha = __expf(mj[j] - mnew);
      mj[j] = mnew;
      float sum = 0.f;
#pragma unroll
      for (int nt = 0; nt < 4; ++nt) {
        float e = __expf(p[nt][j] - mnew);
        p[nt][j] = e;
        sum += e;
      }
#pragma unroll
      for (int msk = 1; msk < 16; msk <<= 1) sum += __shfl_xor(sum, msk);
      lj[j] = lj[j] * alpha + sum;
#pragma unroll
      for (int nt2 = 0; nt2 < 8; ++nt2) oa[nt2][j] *= alpha;
    }

    // P -> LDS (per-wave), then PV
#pragma unroll
    for (int nt = 0; nt < 4; ++nt)
#pragma unroll
      for (int j = 0; j < 4; ++j)
        Pl[(w * 16 + hi * 4 + j) * 72 + nt * 16 + lr] = f2b(p[nt][j]);
    __builtin_amdgcn_sched_barrier(0);

    bf16x8 pa[2];
#pragma unroll
    for (int ks2 = 0; ks2 < 2; ++ks2)
      pa[ks2] = __builtin_bit_cast(bf16x8,
                 *(const u16x8*)&Pl[(w * 16 + lr) * 72 + ks2 * 32 + hi * 8]);
#pragma unroll
    for (int nt2 = 0; nt2 < 8; ++nt2)
#pragma unroll
      for (int ks2 = 0; ks2 < 2; ++ks2) {
        int d = nt2 * 16 + lr;
        int kv = ks2 * 32 + hi * 8;
        bf16x8 vf = __builtin_bit_cast(bf16x8,
                     *(const u16x8*)&Vt[d * 72 + (kv ^ (((d >> 3) & 7) << 3))]);
        oa[nt2] = mfma16x16x32(pa[ks2], vf, oa[nt2]);
      }
  }

  // epilogue
#pragma unroll
  for (int nt2 = 0; nt2 < 8; ++nt2)
#pragma unroll
    for (int j = 0; j < 4; ++j) {
      int row = t0 + w * 16 + hi * 4 + j;
      int d = nt2 * 16 + lr;
      og[((size_t)row * Hm + h) * HDm + d] = f2b(oa[nt2][j] / lj[j]);
    }
}

// ---------------------------------------------------------------------------
extern "C" void kernel_launch(void* const* d_in, const int* in_sizes, int n_in,
                              void* d_out, int out_size, void* d_ws, size_t ws_size,
                              hipStream_t stream) {
  (void)in_sizes; (void)n_in; (void)out_size; (void)ws_size;
  const int*   ids = (const int*)d_in[0];
  const float* emb = (const float*)d_in[1];
  const float* Wq  = (const float*)d_in[2];
  const float* Wk  = (const float*)d_in[3];
  const float* Wv  = (const float*)d_in[4];
  const float* Wo  = (const float*)d_in[5];
  const float* qn  = (const float*)d_in[6];
  const float* kn  = (const float*)d_in[7];
  const float* W1  = (const float*)d_in[8];
  const float* W2  = (const float*)d_in[9];
  const float* W3  = (const float*)d_in[10];
  const float* ln1 = (const float*)d_in[11];
  const float* ln2 = (const float*)d_in[12];
  const float* lnf = (const float*)d_in[13];

  char* p = (char*)d_ws;
  float* xf          = (float*)p;          p += (size_t)Tm * Dm * 4;
  unsigned short* hb = (unsigned short*)p; p += (size_t)Tm * Dm * 2;
  unsigned short* qb = (unsigned short*)p; p += (size_t)Tm * Hm * HDm * 2;
  unsigned short* kb = (unsigned short*)p; p += (size_t)Tm * KVm * HDm * 2;
  unsigned short* vb = (unsigned short*)p; p += (size_t)Tm * KVm * HDm * 2;
  unsigned short* ob = (unsigned short*)p; p += (size_t)Tm * Hm * HDm * 2;
  unsigned short* wt = (unsigned short*)p; p += (size_t)Dm * FFm * 2;   // 25.2MB JIT slot
  float* cosT        = (float*)p;          p += (size_t)Tm * 64 * 4;
  float* sinT        = (float*)p;          p += (size_t)Tm * 64 * 4;
  unsigned short* g1 = qb;  // FFN reuses attn q/k/v/o span (exactly T*FF bf16)

  rope_tables_k<<<Tm, 64, 0, stream>>>(cosT, sinT);
  embed_k<<<Tm, 256, 0, stream>>>(ids, emb, xf);

  for (int l = 0; l < 2; ++l) {
    const float* Wq_l = Wq + (size_t)l * Dm * (Hm * HDm);
    const float* Wk_l = Wk + (size_t)l * Dm * (KVm * HDm);
    const float* Wv_l = Wv + (size_t)l * Dm * (KVm * HDm);
    const float* Wo_l = Wo + (size_t)l * (Hm * HDm) * Dm;
    const float* W1_l = W1 + (size_t)l * Dm * FFm;
    const float* W2_l = W2 + (size_t)l * Dm * FFm;
    const float* W3_l = W3 + (size_t)l * FFm * Dm;

    rmsnorm_k<<<Tm, 256, 0, stream>>>(xf, ln1 + (size_t)l * Dm, hb);

    // QKV
    cvtT_k<<<dim3((Hm * HDm) / 64, Dm / 64), 256, 0, stream>>>(Wq_l, wt, Dm, Hm * HDm);
    gemm_k<0, false, false><<<dim3(Tm / 128, (Hm * HDm) / 128), 256, 0, stream>>>(
        hb, wt, qb, Hm * HDm, Dm);
    cvtT_k<<<dim3((KVm * HDm) / 64, Dm / 64), 256, 0, stream>>>(Wk_l, wt, Dm, KVm * HDm);
    gemm_k<0, false, false><<<dim3(Tm / 128, (KVm * HDm) / 128), 256, 0, stream>>>(
        hb, wt, kb, KVm * HDm, Dm);
    cvtT_k<<<dim3((KVm * HDm) / 64, Dm / 64), 256, 0, stream>>>(Wv_l, wt, Dm, KVm * HDm);
    gemm_k<0, false, false><<<dim3(Tm / 128, (KVm * HDm) / 128), 256, 0, stream>>>(
        hb, wt, vb, KVm * HDm, Dm);

    qknorm_rope_k<<<(Tm * Hm) / 4, 256, 0, stream>>>(qb, qn + (size_t)l * HDm, cosT, sinT, Hm);
    qknorm_rope_k<<<(Tm * KVm) / 4, 256, 0, stream>>>(kb, kn + (size_t)l * HDm, cosT, sinT, KVm);

    attn_k<<<dim3(Tm / 64, Hm), 256, 0, stream>>>(qb, kb, vb, ob);

    cvtT_k<<<dim3(Dm / 64, (Hm * HDm) / 64), 256, 0, stream>>>(Wo_l, wt, Hm * HDm, Dm);
    gemm_k<1, false, false><<<dim3(Tm / 128, Dm / 128), 256, 0, stream>>>(
        ob, wt, xf, Dm, Hm * HDm);

    rmsnorm_k<<<Tm, 256, 0, stream>>>(xf, ln2 + (size_t)l * Dm, hb);

    cvtT_k<<<dim3(FFm / 64, Dm / 64), 256, 0, stream>>>(W1_l, wt, Dm, FFm);
    gemm_k<0, false, false><<<dim3(Tm / 128, FFm / 128), 256, 0, stream>>>(
        hb, wt, g1, FFm, Dm);
    cvtT_k<<<dim3(FFm / 64, Dm / 64), 256, 0, stream>>>(W2_l, wt, Dm, FFm);
    gemm_k<2, false, false><<<dim3(Tm / 128, FFm / 128), 256, 0, stream>>>(
        hb, wt, g1, FFm, Dm);
    cvtT_k<<<dim3(Dm / 64, FFm / 64), 256, 0, stream>>>(W3_l, wt, FFm, Dm);
    gemm_k<1, false, false><<<dim3(Tm / 128, Dm / 128), 256, 0, stream>>>(
        g1, wt, xf, Dm, FFm);
  }

  rmsnorm_k<<<Tm, 256, 0, stream>>>(xf, lnf, hb);
  // logits: B = emb fp32 [V][D] used natively as B^T; fp32 store to d_out
  gemm_k<0, true, true><<<dim3(Tm / 128, Vm / 128), 256, 0, stream>>>(
      hb, emb, d_out, Vm, Dm);
}

// Round 4
// 1858.174 us; speedup vs baseline: 3.3099x; 1.0383x over previous
//
#include <hip/hip_runtime.h>
#include <math.h>

typedef float f32x4 __attribute__((ext_vector_type(4)));
typedef __bf16 bf16x8 __attribute__((ext_vector_type(8)));
typedef unsigned short u16x8 __attribute__((ext_vector_type(8)));

static constexpr int Dm  = 2048;
static constexpr int Tm  = 2048;
static constexpr int Hm  = 16;
static constexpr int KVm = 8;
static constexpr int HDm = 128;
static constexpr int FFm = 6144;
static constexpr int Vm  = 32000;

__device__ __forceinline__ float b2f(unsigned short u) {
  unsigned int x = ((unsigned int)u) << 16;
  return __builtin_bit_cast(float, x);
}
__device__ __forceinline__ unsigned short f2b(float f) {
  unsigned int x = __builtin_bit_cast(unsigned int, f);
  x += 0x7fffu + ((x >> 16) & 1u);   // RTNE
  return (unsigned short)(x >> 16);
}
__device__ __forceinline__ f32x4 mfma16x16x32(bf16x8 a, bf16x8 b, f32x4 c) {
  return __builtin_amdgcn_mfma_f32_16x16x32_bf16(a, b, c, 0, 0, 0);
}

// async global->LDS, 16B per lane; LDS dest = wave-uniform base + lane*16
__device__ __forceinline__ void gload16(const unsigned short* g, unsigned short* lds) {
  __builtin_amdgcn_global_load_lds(
      (const __attribute__((address_space(1))) unsigned int*)g,
      (__attribute__((address_space(3))) unsigned int*)lds, 16, 0, 0);
}

// bijective chunked XCD swizzle (m204): consecutive new-ids share bn AND XCD
__device__ __forceinline__ int xcd_swz(int o, int nwg) {
  int q = nwg >> 3, r8 = nwg & 7;
  int xcd = o & 7, pos = o >> 3;
  return (xcd < r8) ? xcd * (q + 1) + pos : r8 * (q + 1) + (xcd - r8) * q + pos;
}

// ---------------------------------------------------------------------------
__global__ void rope_tables_k(float* __restrict__ cosT, float* __restrict__ sinT) {
  int t = blockIdx.x;
  int i = threadIdx.x;      // 0..63
  double inv = pow(1000000.0, -(double)i / 64.0);
  double ang = (double)t * inv;
  cosT[t * 64 + i] = (float)cos(ang);
  sinT[t * 64 + i] = (float)sin(ang);
}

__global__ __launch_bounds__(256) void embed_k(const int* __restrict__ ids,
                                               const float* __restrict__ emb,
                                               float* __restrict__ x) {
  int t = blockIdx.x;
  int d0 = threadIdx.x * 8;
  int id = ids[t];
  const float* src = emb + (size_t)id * Dm + d0;
  float* dst = x + (size_t)t * Dm + d0;
  *(f32x4*)dst       = *(const f32x4*)src;
  *(f32x4*)(dst + 4) = *(const f32x4*)(src + 4);
}

__global__ __launch_bounds__(256) void rmsnorm_k(const float* __restrict__ x,
                                                 const float* __restrict__ g,
                                                 unsigned short* __restrict__ y) {
  int t = blockIdx.x;
  const float* xr = x + (size_t)t * Dm;
  float vals[8];
  float s = 0.f;
#pragma unroll
  for (int i = 0; i < 8; ++i) {
    float vv = xr[threadIdx.x + i * 256];
    vals[i] = vv;
    s += vv * vv;
  }
#pragma unroll
  for (int off = 32; off; off >>= 1) s += __shfl_xor(s, off);
  __shared__ float red[4];
  if ((threadIdx.x & 63) == 0) red[threadIdx.x >> 6] = s;
  __syncthreads();
  s = (red[0] + red[1]) + (red[2] + red[3]);
  float r = rsqrtf(s * (1.f / Dm) + 1e-6f);
  unsigned short* yr = y + (size_t)t * Dm;
#pragma unroll
  for (int i = 0; i < 8; ++i) {
    int d = threadIdx.x + i * 256;
    yr[d] = f2b(vals[i] * r * g[d]);
  }
}

__global__ __launch_bounds__(256) void qknorm_rope_k(unsigned short* __restrict__ q,
                                                     const float* __restrict__ nrm,
                                                     const float* __restrict__ cosT,
                                                     const float* __restrict__ sinT,
                                                     int nheads) {
  int gw = (int)((blockIdx.x * blockDim.x + threadIdx.x) >> 6);
  int lane = threadIdx.x & 63;
  int t = gw / nheads, h = gw % nheads;
  unsigned short* row = q + ((size_t)t * nheads + h) * HDm;
  float x1 = b2f(row[lane]);
  float x2 = b2f(row[lane + 64]);
  float s = x1 * x1 + x2 * x2;
#pragma unroll
  for (int off = 32; off; off >>= 1) s += __shfl_xor(s, off);
  float r = rsqrtf(s * (1.f / HDm) + 1e-6f);
  float y1 = x1 * r * nrm[lane];
  float y2 = x2 * r * nrm[lane + 64];
  float c = cosT[t * 64 + lane];
  float sn = sinT[t * 64 + lane];
  row[lane]      = f2b(y1 * c - y2 * sn);
  row[lane + 64] = f2b(y2 * c + y1 * sn);
}

// Weight convert+transpose: W fp32 [K][N] -> Wt bf16 [N][K]
__global__ __launch_bounds__(256) void cvtT_k(const float* __restrict__ W,
                                              unsigned short* __restrict__ Wt,
                                              int K, int N) {
  __shared__ __align__(16) unsigned short tile[64][68];
  const int n0 = blockIdx.x * 64, k0 = blockIdx.y * 64;
  const int tid = threadIdx.x;
#pragma unroll
  for (int i = 0; i < 4; ++i) {
    int e = tid + i * 256;
    int r = e >> 4, c4 = (e & 15) * 4;
    f32x4 v = *(const f32x4*)(W + (size_t)(k0 + r) * N + n0 + c4);
    tile[r][c4 + 0] = f2b(v.x);
    tile[r][c4 + 1] = f2b(v.y);
    tile[r][c4 + 2] = f2b(v.z);
    tile[r][c4 + 3] = f2b(v.w);
  }
  __syncthreads();
#pragma unroll
  for (int i = 0; i < 2; ++i) {
    int e = tid + i * 256;
    int rr = e >> 3, cc = (e & 7) * 8;
    u16x8 o;
#pragma unroll
    for (int j = 0; j < 8; ++j) o[j] = tile[cc + j][rr];
    *(u16x8*)(Wt + (size_t)(n0 + rr) * K + k0 + cc) = o;
  }
}

// ---------------------------------------------------------------------------
// GEMM: C[M,N] = A[M,K] @ B^T. A bf16 [M][K]; B [N][K] (bf16, or fp32 if BF32).
// m97 structure: global_load_lds w=16, linear LDS [128][32], 2-barrier K-loop.
// EPI=0: store (bf16, or fp32 if OUTF32). EPI=1: C f32 +=. EPI=2: bf16 silu-mult.
template <int EPI, bool BF32, bool OUTF32>
__global__ __launch_bounds__(256) void gemm_k(const unsigned short* __restrict__ A,
                                              const void* __restrict__ B,
                                              void* __restrict__ C,
                                              int N, int K) {
  __shared__ __align__(16) unsigned short As[128 * 32];
  __shared__ __align__(16) unsigned short Bs[128 * 32];
  const int tid = threadIdx.x;
  const int nwg = gridDim.x * gridDim.y;
  const int nid = xcd_swz(blockIdx.x + gridDim.x * blockIdx.y, nwg);
  const int bm = nid % gridDim.x, bn = nid / gridDim.x;
  const int w = tid >> 6, lane = tid & 63;
  const int wm = (w >> 1) * 64, wn = (w & 1) * 64;
  const int lr = lane & 15, hi = lane >> 4, kq = hi * 8;
  const int rowA0 = bm * 128, colB0 = bn * 128;

  // staging geometry: chunk = 1KB = 16 rows x 32 cols bf16; lane l -> LDS byte l*16
  const int sr = lane >> 2;          // row within chunk
  const int sc = (lane & 3) * 8;     // col (elems)
  const unsigned short* a0 = A + (size_t)(rowA0 + (w * 2 + 0) * 16 + sr) * K + sc;
  const unsigned short* a1 = A + (size_t)(rowA0 + (w * 2 + 1) * 16 + sr) * K + sc;
  unsigned short* la0 = &As[(w * 2 + 0) * 512];
  unsigned short* la1 = &As[(w * 2 + 1) * 512];
  const unsigned short* b0 = nullptr; const unsigned short* b1 = nullptr;
  unsigned short* lb0 = &Bs[(w * 2 + 0) * 512];
  unsigned short* lb1 = &Bs[(w * 2 + 1) * 512];
  if (!BF32) {
    b0 = (const unsigned short*)B + (size_t)(colB0 + (w * 2 + 0) * 16 + sr) * K + sc;
    b1 = (const unsigned short*)B + (size_t)(colB0 + (w * 2 + 1) * 16 + sr) * K + sc;
  }

  f32x4 acc[4][4] = {};

  for (int k0 = 0; k0 < K; k0 += 32) {
    __syncthreads();
    gload16(a0 + k0, la0);
    gload16(a1 + k0, la1);
    if (!BF32) {
      gload16(b0 + k0, lb0);
      gload16(b1 + k0, lb1);
    } else {
#pragma unroll
      for (int i = 0; i < 2; ++i) {
        int e = tid + i * 256;
        int rr = e >> 2, cc = (e & 3) * 8;
        const float* bp = (const float*)B + (size_t)(colB0 + rr) * K + k0 + cc;
        f32x4 v0 = *(const f32x4*)bp;
        f32x4 v1 = *(const f32x4*)(bp + 4);
        u16x8 o;
        o[0] = f2b(v0.x); o[1] = f2b(v0.y); o[2] = f2b(v0.z); o[3] = f2b(v0.w);
        o[4] = f2b(v1.x); o[5] = f2b(v1.y); o[6] = f2b(v1.z); o[7] = f2b(v1.w);
        *(u16x8*)&Bs[rr * 32 + cc] = o;
      }
    }
    __syncthreads();   // compiler drains vmcnt(0)+lgkmcnt(0) before s_barrier

    bf16x8 av[4], bv[4];
#pragma unroll
    for (int m = 0; m < 4; ++m)
      av[m] = __builtin_bit_cast(bf16x8, *(const u16x8*)&As[(wm + m * 16 + lr) * 32 + kq]);
#pragma unroll
    for (int n = 0; n < 4; ++n)
      bv[n] = __builtin_bit_cast(bf16x8, *(const u16x8*)&Bs[(wn + n * 16 + lr) * 32 + kq]);
#pragma unroll
    for (int m = 0; m < 4; ++m)
#pragma unroll
      for (int n = 0; n < 4; ++n)
        acc[m][n] = mfma16x16x32(av[m], bv[n], acc[m][n]);
  }

  // C/D layout: col=lane&15, row=(lane>>4)*4+reg  [verified]
  const int r0 = rowA0 + wm + hi * 4;
  const int c0 = colB0 + wn + lr;
#pragma unroll
  for (int m = 0; m < 4; ++m)
#pragma unroll
    for (int n = 0; n < 4; ++n)
#pragma unroll
      for (int j = 0; j < 4; ++j) {
        int r = r0 + m * 16 + j;
        int c = c0 + n * 16;
        size_t idx = (size_t)r * N + c;
        if (EPI == 0) {
          if (OUTF32) ((float*)C)[idx] = acc[m][n][j];
          else        ((unsigned short*)C)[idx] = f2b(acc[m][n][j]);
        } else if (EPI == 1) {
          ((float*)C)[idx] += acc[m][n][j];
        } else {
          unsigned short* Cb = (unsigned short*)C;
          float gg = b2f(Cb[idx]);
          gg = gg / (1.f + __expf(-gg));   // silu of previously-stored h@W1
          Cb[idx] = f2b(gg * acc[m][n][j]);
        }
      }
}

// ---------------------------------------------------------------------------
// MFMA flash attention, GQA G=2. Block: 4 waves, 64 q-rows, head h.
__global__ __launch_bounds__(256) void attn_k(const unsigned short* __restrict__ qg,
                                              const unsigned short* __restrict__ kg,
                                              const unsigned short* __restrict__ vg,
                                              unsigned short* __restrict__ og) {
  __shared__ __align__(16) unsigned short Ks[64 * 128];   // swizzled rows of K
  __shared__ __align__(16) unsigned short Vt[128 * 72];   // Vt[d][kv^swz]
  __shared__ __align__(16) unsigned short Pl[4 * 16 * 72];// per-wave P rows
  const int h = blockIdx.y, bx = blockIdx.x, t0 = bx * 64;
  const int w = threadIdx.x >> 6, lane = threadIdx.x & 63;
  const int lr = lane & 15, hi = lane >> 4;   // hi 0..3
  const int kvh = h >> 1;

  bf16x8 qa[4];
  {
    const unsigned short* qrow = qg + ((size_t)(t0 + w * 16 + lr) * Hm + h) * HDm;
#pragma unroll
    for (int ks = 0; ks < 4; ++ks)
      qa[ks] = __builtin_bit_cast(bf16x8, *(const u16x8*)(qrow + ks * 32 + hi * 8));
  }

  f32x4 oa[8] = {};
  float mj[4], lj[4];
#pragma unroll
  for (int j = 0; j < 4; ++j) { mj[j] = -3.0e38f; lj[j] = 0.f; }

  const int ntiles = bx + 1;
  for (int tile = 0; tile < ntiles; ++tile) {
    const int s0 = tile * 64;
    __syncthreads();
#pragma unroll
    for (int i = 0; i < 4; ++i) {
      int e = threadIdx.x + i * 256;
      int r = e >> 4, c = (e & 15) * 8;
      size_t base = ((size_t)(s0 + r) * KVm + kvh) * HDm + c;
      u16x8 kk = *(const u16x8*)(kg + base);
      int kbyte = (r * 256 + c * 2) ^ ((r & 7) << 4);
      *(u16x8*)((char*)Ks + kbyte) = kk;
      u16x8 vv = *(const u16x8*)(vg + base);
#pragma unroll
      for (int j = 0; j < 8; ++j) {
        int d = c + j;
        Vt[d * 72 + (r ^ (((d >> 3) & 7) << 3))] = vv[j];
      }
    }
    __syncthreads();

    f32x4 s[4] = {};
#pragma unroll
    for (int ks = 0; ks < 4; ++ks)
#pragma unroll
      for (int nt = 0; nt < 4; ++nt) {
        int krow = nt * 16 + lr;
        int kbyte = (krow * 256 + (ks * 32 + hi * 8) * 2) ^ ((krow & 7) << 4);
        bf16x8 kf = __builtin_bit_cast(bf16x8, *(const u16x8*)((char*)Ks + kbyte));
        s[nt] = mfma16x16x32(qa[ks], kf, s[nt]);
      }

    float p[4][4];
    const bool maskt = (tile == ntiles - 1);
#pragma unroll
    for (int nt = 0; nt < 4; ++nt)
#pragma unroll
      for (int j = 0; j < 4; ++j) {
        float val = s[nt][j] * 0.08838834764831845f;
        if (maskt && (s0 + nt * 16 + lr) > (t0 + w * 16 + hi * 4 + j)) val = -1e30f;
        p[nt][j] = val;
      }

#pragma unroll
    for (int j = 0; j < 4; ++j) {
      float mx = fmaxf(fmaxf(p[0][j], p[1][j]), fmaxf(p[2][j], p[3][j]));
#pragma unroll
      for (int msk = 1; msk < 16; msk <<= 1) mx = fmaxf(mx, __shfl_xor(mx, msk));
      float mnew = fmaxf(mj[j], mx);
      float alpha = __expf(mj[j] - mnew);
      mj[j] = mnew;
      float sum = 0.f;
#pragma unroll
      for (int nt = 0; nt < 4; ++nt) {
        float e = __expf(p[nt][j] - mnew);
        p[nt][j] = e;
        sum += e;
      }
#pragma unroll
      for (int msk = 1; msk < 16; msk <<= 1) sum += __shfl_xor(sum, msk);
      lj[j] = lj[j] * alpha + sum;
#pragma unroll
      for (int nt2 = 0; nt2 < 8; ++nt2) oa[nt2][j] *= alpha;
    }

#pragma unroll
    for (int nt = 0; nt < 4; ++nt)
#pragma unroll
      for (int j = 0; j < 4; ++j)
        Pl[(w * 16 + hi * 4 + j) * 72 + nt * 16 + lr] = f2b(p[nt][j]);
    __builtin_amdgcn_sched_barrier(0);

    bf16x8 pa[2];
#pragma unroll
    for (int ks2 = 0; ks2 < 2; ++ks2)
      pa[ks2] = __builtin_bit_cast(bf16x8,
                 *(const u16x8*)&Pl[(w * 16 + lr) * 72 + ks2 * 32 + hi * 8]);
#pragma unroll
    for (int nt2 = 0; nt2 < 8; ++nt2)
#pragma unroll
      for (int ks2 = 0; ks2 < 2; ++ks2) {
        int d = nt2 * 16 + lr;
        int kv = ks2 * 32 + hi * 8;
        bf16x8 vf = __builtin_bit_cast(bf16x8,
                     *(const u16x8*)&Vt[d * 72 + (kv ^ (((d >> 3) & 7) << 3))]);
        oa[nt2] = mfma16x16x32(pa[ks2], vf, oa[nt2]);
      }
  }

#pragma unroll
  for (int nt2 = 0; nt2 < 8; ++nt2)
#pragma unroll
    for (int j = 0; j < 4; ++j) {
      int row = t0 + w * 16 + hi * 4 + j;
      int d = nt2 * 16 + lr;
      og[((size_t)row * Hm + h) * HDm + d] = f2b(oa[nt2][j] / lj[j]);
    }
}

// ---------------------------------------------------------------------------
extern "C" void kernel_launch(void* const* d_in, const int* in_sizes, int n_in,
                              void* d_out, int out_size, void* d_ws, size_t ws_size,
                              hipStream_t stream) {
  (void)in_sizes; (void)n_in; (void)out_size; (void)ws_size;
  const int*   ids = (const int*)d_in[0];
  const float* emb = (const float*)d_in[1];
  const float* Wq  = (const float*)d_in[2];
  const float* Wk  = (const float*)d_in[3];
  const float* Wv  = (const float*)d_in[4];
  const float* Wo  = (const float*)d_in[5];
  const float* qn  = (const float*)d_in[6];
  const float* kn  = (const float*)d_in[7];
  const float* W1  = (const float*)d_in[8];
  const float* W2  = (const float*)d_in[9];
  const float* W3  = (const float*)d_in[10];
  const float* ln1 = (const float*)d_in[11];
  const float* ln2 = (const float*)d_in[12];
  const float* lnf = (const float*)d_in[13];

  char* p = (char*)d_ws;
  float* xf          = (float*)p;          p += (size_t)Tm * Dm * 4;
  unsigned short* hb = (unsigned short*)p; p += (size_t)Tm * Dm * 2;
  unsigned short* qb = (unsigned short*)p; p += (size_t)Tm * Hm * HDm * 2;
  unsigned short* kb = (unsigned short*)p; p += (size_t)Tm * KVm * HDm * 2;
  unsigned short* vb = (unsigned short*)p; p += (size_t)Tm * KVm * HDm * 2;
  unsigned short* ob = (unsigned short*)p; p += (size_t)Tm * Hm * HDm * 2;
  unsigned short* wt = (unsigned short*)p; p += (size_t)Dm * FFm * 2;   // 25.2MB JIT slot
  float* cosT        = (float*)p;          p += (size_t)Tm * 64 * 4;
  float* sinT        = (float*)p;          p += (size_t)Tm * 64 * 4;
  unsigned short* g1 = qb;  // FFN reuses attn q/k/v/o span

  rope_tables_k<<<Tm, 64, 0, stream>>>(cosT, sinT);
  embed_k<<<Tm, 256, 0, stream>>>(ids, emb, xf);

  for (int l = 0; l < 2; ++l) {
    const float* Wq_l = Wq + (size_t)l * Dm * (Hm * HDm);
    const float* Wk_l = Wk + (size_t)l * Dm * (KVm * HDm);
    const float* Wv_l = Wv + (size_t)l * Dm * (KVm * HDm);
    const float* Wo_l = Wo + (size_t)l * (Hm * HDm) * Dm;
    const float* W1_l = W1 + (size_t)l * Dm * FFm;
    const float* W2_l = W2 + (size_t)l * Dm * FFm;
    const float* W3_l = W3 + (size_t)l * FFm * Dm;

    rmsnorm_k<<<Tm, 256, 0, stream>>>(xf, ln1 + (size_t)l * Dm, hb);

    cvtT_k<<<dim3((Hm * HDm) / 64, Dm / 64), 256, 0, stream>>>(Wq_l, wt, Dm, Hm * HDm);
    gemm_k<0, false, false><<<dim3(Tm / 128, (Hm * HDm) / 128), 256, 0, stream>>>(
        hb, wt, qb, Hm * HDm, Dm);
    cvtT_k<<<dim3((KVm * HDm) / 64, Dm / 64), 256, 0, stream>>>(Wk_l, wt, Dm, KVm * HDm);
    gemm_k<0, false, false><<<dim3(Tm / 128, (KVm * HDm) / 128), 256, 0, stream>>>(
        hb, wt, kb, KVm * HDm, Dm);
    cvtT_k<<<dim3((KVm * HDm) / 64, Dm / 64), 256, 0, stream>>>(Wv_l, wt, Dm, KVm * HDm);
    gemm_k<0, false, false><<<dim3(Tm / 128, (KVm * HDm) / 128), 256, 0, stream>>>(
        hb, wt, vb, KVm * HDm, Dm);

    qknorm_rope_k<<<(Tm * Hm) / 4, 256, 0, stream>>>(qb, qn + (size_t)l * HDm, cosT, sinT, Hm);
    qknorm_rope_k<<<(Tm * KVm) / 4, 256, 0, stream>>>(kb, kn + (size_t)l * HDm, cosT, sinT, KVm);

    attn_k<<<dim3(Tm / 64, Hm), 256, 0, stream>>>(qb, kb, vb, ob);

    cvtT_k<<<dim3(Dm / 64, (Hm * HDm) / 64), 256, 0, stream>>>(Wo_l, wt, Hm * HDm, Dm);
    gemm_k<1, false, false><<<dim3(Tm / 128, Dm / 128), 256, 0, stream>>>(
        ob, wt, xf, Dm, Hm * HDm);

    rmsnorm_k<<<Tm, 256, 0, stream>>>(xf, ln2 + (size_t)l * Dm, hb);

    cvtT_k<<<dim3(FFm / 64, Dm / 64), 256, 0, stream>>>(W1_l, wt, Dm, FFm);
    gemm_k<0, false, false><<<dim3(Tm / 128, FFm / 128), 256, 0, stream>>>(
        hb, wt, g1, FFm, Dm);
    cvtT_k<<<dim3(FFm / 64, Dm / 64), 256, 0, stream>>>(W2_l, wt, Dm, FFm);
    gemm_k<2, false, false><<<dim3(Tm / 128, FFm / 128), 256, 0, stream>>>(
        hb, wt, g1, FFm, Dm);
    cvtT_k<<<dim3(Dm / 64, FFm / 64), 256, 0, stream>>>(W3_l, wt, FFm, Dm);
    gemm_k<1, false, false><<<dim3(Tm / 128, Dm / 128), 256, 0, stream>>>(
        g1, wt, xf, Dm, FFm);
  }

  rmsnorm_k<<<Tm, 256, 0, stream>>>(xf, lnf, hb);
  gemm_k<0, true, true><<<dim3(Tm / 128, Vm / 128), 256, 0, stream>>>(
      hb, emb, d_out, Vm, Dm);
}